// Round 3
// baseline (230.125 us; speedup 1.0000x reference)
//
#include <hip/hip_runtime.h>
#include <cstdint>

#define BB 32
#define PP 131072
#define NEG_RATIO 3

typedef float v4f __attribute__((ext_vector_type(4)));

// Workspace accumulators (zeroed via hipMemsetAsync each launch).
struct Ws {
  float sum_sl1[BB];     // per-batch sum of smoothL1 * pos
  float sum_ce_all[BB];  // per-batch sum of CE over all priors
  float sum_ce_pos[BB];  // per-batch sum of CE over positives
  float ce_neg[BB];      // per-batch CE sum over selected negatives (case-2 only)
  int   num_pos[BB];
};

__device__ __forceinline__ float sl1sum(v4f a, v4f b) {
  float dx = fabsf(a.x - b.x), dy = fabsf(a.y - b.y),
        dz = fabsf(a.z - b.z), dw = fabsf(a.w - b.w);
  float sx = dx < 1.0f ? 0.5f * dx * dx : dx - 0.5f;
  float sy = dy < 1.0f ? 0.5f * dy * dy : dy - 0.5f;
  float sz = dz < 1.0f ? 0.5f * dz * dz : dz - 0.5f;
  float sw = dw < 1.0f ? 0.5f * dw * dw : dw - 0.5f;
  return (sx + sy) + (sz + sw);
}

__device__ __forceinline__ float ce_fast(float c0, float c1, int t) {
  float m = fmaxf(c0, c1);
  float d = fabsf(c0 - c1);
  float lse = m + __logf(1.0f + __expf(-d));
  return lse - (t ? c1 : c0);
}

// exact-ish version for the (never-taken on bench data) select path
__device__ __forceinline__ float ce_of(float c0, float c1, int t) {
  float m = fmaxf(c0, c1), mn = fminf(c0, c1);
  float lse = m + log1pf(expf(mn - m));
  return lse - (t ? c1 : c0);
}

// ---------------- K_loc: smooth-L1 masked sum (loc + loct + conft) ----------------
// Block b covers priors [1024b, 1024b+1024); lane handles priors p0+256k, k=0..3.
// Every load instruction is lane-contiguous (fully coalesced). All 12 loads are
// issued before any use (sched_barrier pins the schedule).
__global__ __launch_bounds__(256) void k_loc(
    const v4f* __restrict__ loc, const v4f* __restrict__ loct,
    const int* __restrict__ tt, Ws* __restrict__ ws) {
  const int tid = threadIdx.x;
  const int b = blockIdx.x;
  const int batch = b >> 7;  // 128 blocks per batch
  const int p0 = b * 1024 + tid;

  const v4f l0 = __builtin_nontemporal_load(loc + p0 + 0);
  const v4f l1 = __builtin_nontemporal_load(loc + p0 + 256);
  const v4f l2 = __builtin_nontemporal_load(loc + p0 + 512);
  const v4f l3 = __builtin_nontemporal_load(loc + p0 + 768);
  const v4f g0 = __builtin_nontemporal_load(loct + p0 + 0);
  const v4f g1 = __builtin_nontemporal_load(loct + p0 + 256);
  const v4f g2 = __builtin_nontemporal_load(loct + p0 + 512);
  const v4f g3 = __builtin_nontemporal_load(loct + p0 + 768);
  const int t0 = tt[p0 + 0];
  const int t1 = tt[p0 + 256];
  const int t2 = tt[p0 + 512];
  const int t3 = tt[p0 + 768];
  __builtin_amdgcn_sched_barrier(0);

  const float m0 = t0 > 0 ? 1.0f : 0.0f, m1 = t1 > 0 ? 1.0f : 0.0f,
              m2 = t2 > 0 ? 1.0f : 0.0f, m3 = t3 > 0 ? 1.0f : 0.0f;
  float a = (m0 * sl1sum(l0, g0) + m1 * sl1sum(l1, g1)) +
            (m2 * sl1sum(l2, g2) + m3 * sl1sum(l3, g3));

#pragma unroll
  for (int off = 32; off; off >>= 1) a += __shfl_down(a, off);

  __shared__ float sred[4];
  const int wave = tid >> 6, lane = tid & 63;
  if (lane == 0) sred[wave] = a;
  __syncthreads();
  if (tid == 0)
    atomicAdd(&ws->sum_sl1[batch], (sred[0] + sred[1]) + (sred[2] + sred[3]));
}

// ---------------- K_conf: CE sums + positive count (conf + conft) ----------------
// Block b covers prior-pairs [512b, 512b+512) = priors [1024b, 1024b+1024).
// Lane handles pairs j0 and j0+256: conf4[j] = (c0,c1,c0,c1) for priors 2j,2j+1;
// int2[j] = labels for the same two priors. All loads coalesced and matched.
__global__ __launch_bounds__(256) void k_conf(
    const v4f* __restrict__ conf4, const int2* __restrict__ tt2,
    Ws* __restrict__ ws) {
  const int tid = threadIdx.x;
  const int b = blockIdx.x;
  const int batch = b >> 7;  // 128 blocks per batch
  const int j0 = b * 512 + tid;

  const v4f ca = conf4[j0 + 0];
  const v4f cb = conf4[j0 + 256];
  const int2 ta = tt2[j0 + 0];
  const int2 tb = tt2[j0 + 256];
  __builtin_amdgcn_sched_barrier(0);

  const float ce0 = ce_fast(ca.x, ca.y, ta.x);
  const float ce1 = ce_fast(ca.z, ca.w, ta.y);
  const float ce2 = ce_fast(cb.x, cb.y, tb.x);
  const float ce3 = ce_fast(cb.z, cb.w, tb.y);
  const float m0 = ta.x > 0 ? 1.0f : 0.0f, m1 = ta.y > 0 ? 1.0f : 0.0f,
              m2 = tb.x > 0 ? 1.0f : 0.0f, m3 = tb.y > 0 ? 1.0f : 0.0f;

  float a_all = (ce0 + ce1) + (ce2 + ce3);
  float a_pos = (m0 * ce0 + m1 * ce1) + (m2 * ce2 + m3 * ce3);
  int   a_np  = (ta.x > 0) + (ta.y > 0) + (tb.x > 0) + (tb.y > 0);

#pragma unroll
  for (int off = 32; off; off >>= 1) {
    a_all += __shfl_down(a_all, off);
    a_pos += __shfl_down(a_pos, off);
    a_np  += __shfl_down(a_np, off);
  }

  __shared__ float s1[4], s2[4];
  __shared__ int s3[4];
  const int wave = tid >> 6, lane = tid & 63;
  if (lane == 0) { s1[wave] = a_all; s2[wave] = a_pos; s3[wave] = a_np; }
  __syncthreads();
  if (tid == 0) {
    atomicAdd(&ws->sum_ce_all[batch], (s1[0] + s1[1]) + (s1[2] + s1[3]));
    atomicAdd(&ws->sum_ce_pos[batch], (s2[0] + s2[1]) + (s2[2] + s2[3]));
    atomicAdd(&ws->num_pos[batch],     s3[0] + s3[1] + s3[2] + s3[3]);
  }
}

// ---------------- K2: general top-k negative selection (case 2) ----------------
// Only runs for batches where num_neg < (P - num_pos). For the bench data this
// never triggers (num_neg = P-1 >= M), so the block exits immediately.
__global__ __launch_bounds__(256) void k_select(
    const float2* __restrict__ conf, const int* __restrict__ conft,
    Ws* __restrict__ ws) {
  const int b = blockIdx.x;
  const int npos = ws->num_pos[b];
  const long long M = (long long)PP - npos;
  long long k = (long long)NEG_RATIO * npos;
  if (k > PP - 1) k = PP - 1;
  if (k >= M) return;   // case 1: sel == everything, finalize handles it
  if (k <= 0) return;   // no negatives selected

  const int tid = threadIdx.x;
  const int rowbase = b * PP;

  __shared__ unsigned hist[2048];
  __shared__ unsigned sh_prefix;
  __shared__ long long sh_kk;

  unsigned prefix = 0;
  long long kk = k;
  const int shifts[3] = {21, 10, 0};
  const int widths[3] = {11, 11, 10};

  for (int pass = 0; pass < 3; ++pass) {
    const int shift = shifts[pass], width = widths[pass];
    const unsigned mask = (1u << width) - 1u;
    for (int j = tid; j < 2048; j += 256) hist[j] = 0;
    __syncthreads();
    for (int i = tid; i < PP; i += 256) {
      const float2 c = conf[rowbase + i];
      const int t = conft[rowbase + i];
      const float score = (t > 0) ? 0.0f : ce_of(c.x, c.y, t);
      const unsigned u = __float_as_uint(score);
      const bool match = (pass == 0) || ((u >> (shift + width)) == prefix);
      if (match) atomicAdd(&hist[(u >> shift) & mask], 1u);
    }
    __syncthreads();
    if (tid == 0) {
      long long c = 0;
      int d = (int)mask;
      for (; d >= 0; --d) {
        c += hist[d];
        if (c >= kk) break;
      }
      if (d < 0) d = 0;  // safety; invariant guarantees break
      sh_prefix = (prefix << width) | (unsigned)d;
      sh_kk = kk - (c - (long long)hist[d]);
    }
    __syncthreads();
    prefix = sh_prefix;
    kk = sh_kk;
    __syncthreads();
  }

  // prefix == T bits (k-th largest score). kk = #ties to include, ascending
  // index order (stable argsort semantics).
  const unsigned Tbits = prefix;
  double local_ce = 0.0;
  __shared__ unsigned wavecnt[4];
  __shared__ long long s_rt;
  if (tid == 0) s_rt = 0;
  __syncthreads();
  const int lane = tid & 63, wave = tid >> 6;

  for (int basei = 0; basei < PP; basei += 256) {
    const int i = basei + tid;
    const float2 c = conf[rowbase + i];
    const int t = conft[rowbase + i];
    const float ce = ce_of(c.x, c.y, t);
    const float score = (t > 0) ? 0.0f : ce;
    const unsigned u = __float_as_uint(score);
    const bool gt = u > Tbits;
    const bool eq = (u == Tbits);
    const unsigned long long bal = __ballot(eq ? 1 : 0);
    if (lane == 0) wavecnt[wave] = (unsigned)__popcll(bal);
    __syncthreads();
    long long cross = s_rt;
    for (int w = 0; w < wave; ++w) cross += wavecnt[w];
    const long long myord = cross + __popcll(bal & ((1ULL << lane) - 1ULL));
    if (gt || (eq && myord < kk)) local_ce += (double)ce;
    __syncthreads();
    if (tid == 0) s_rt += (long long)wavecnt[0] + wavecnt[1] + wavecnt[2] + wavecnt[3];
    __syncthreads();
  }

#pragma unroll
  for (int off = 32; off; off >>= 1) local_ce += __shfl_down(local_ce, off);
  __shared__ double s_ce[4];
  if (lane == 0) s_ce[wave] = local_ce;
  __syncthreads();
  if (tid == 0) ws->ce_neg[b] = (float)(s_ce[0] + s_ce[1] + s_ce[2] + s_ce[3]);
}

// ---------------- K3: finalize ----------------
__global__ __launch_bounds__(64) void k_final(const Ws* __restrict__ ws,
                                              float* __restrict__ out) {
  const int tid = threadIdx.x;
  double np_d = 0.0, ce_sel = 0.0, cnt = 0.0, sl1 = 0.0;
  if (tid < BB) {
    const int npos = ws->num_pos[tid];
    const long long M = (long long)PP - npos;
    long long k = (long long)NEG_RATIO * npos;
    if (k > PP - 1) k = PP - 1;
    np_d = (double)npos;
    sl1 = (double)ws->sum_sl1[tid];
    if (k >= M) {  // case 1: sel covers every prior
      ce_sel = (double)ws->sum_ce_all[tid];
      cnt = (double)PP;
    } else {
      const long long kc = k > 0 ? k : 0;
      ce_sel = (double)ws->sum_ce_pos[tid] + (double)ws->ce_neg[tid];
      cnt = (double)(npos + kc);
    }
  }
#pragma unroll
  for (int off = 32; off; off >>= 1) {
    np_d   += __shfl_down(np_d, off);
    ce_sel += __shfl_down(ce_sel, off);
    cnt    += __shfl_down(cnt, off);
    sl1    += __shfl_down(sl1, off);
  }
  if (tid == 0) {
    const double N = np_d;
    out[0] = (float)(sl1 / (4.0 * N * N));
    out[1] = (float)(ce_sel / cnt / N);
  }
}

extern "C" void kernel_launch(void* const* d_in, const int* in_sizes, int n_in,
                              void* d_out, int out_size, void* d_ws, size_t ws_size,
                              hipStream_t stream) {
  const v4f*    loc   = (const v4f*)d_in[0];
  const v4f*    conf4 = (const v4f*)d_in[1];
  const float2* conf  = (const float2*)d_in[1];
  const v4f*    loct  = (const v4f*)d_in[2];
  const int*    cnft  = (const int*)d_in[3];
  const int2*   cnft2 = (const int2*)d_in[3];
  Ws* ws = (Ws*)d_ws;

  hipMemsetAsync(d_ws, 0, sizeof(Ws), stream);
  // k_conf first: produces num_pos for k_select.
  k_conf<<<dim3((BB * PP) / 1024), dim3(256), 0, stream>>>(conf4, cnft2, ws);
  k_loc<<<dim3((BB * PP) / 1024), dim3(256), 0, stream>>>(loc, loct, cnft, ws);
  k_select<<<dim3(BB), dim3(256), 0, stream>>>(conf, cnft, ws);
  k_final<<<dim3(1), dim3(64), 0, stream>>>(ws, (float*)d_out);
}